// Round 5
// baseline (192.694 us; speedup 1.0000x reference)
//
#include <hip/hip_runtime.h>
#include <cstdint>
#include <cstddef>

#define HW 524288      // H*W = 512*1024
#define HW4 131072     // float4/int4 groups per channel
#define NBIN 1024      // lovasz error histogram bins over [0,2]

// ws layout (bytes):
//   0    : double acc[16][8]  {cnt,cx,cy,sx,sy,sxx,syy,seedfg}     1024 B
//   1024 : double seedbg[2]                                          16 B
//   1040 : float  lov[16]                                            64 B
//   1104 : u32    ctr                                                 4 B
//   4096 : u64    ghist[16][NBIN]  (lo32=neg count, hi32=pos)    131072 B
// memset range: [0, 135168)

__device__ __forceinline__ float wred(float v) {
#pragma unroll
  for (int o = 32; o > 0; o >>= 1) v += __shfl_xor(v, o, 64);
  return v;
}

__device__ __forceinline__ float fsig(float x) {
  return __builtin_amdgcn_rcpf(1.f + __expf(-x));
}
__device__ __forceinline__ float ftanh(float x) {
  return 1.f - 2.f * __builtin_amdgcn_rcpf(__expf(2.f * x) + 1.f);
}

// ---------------- pass1: masked per-instance sums only ----------------
// grid (256, B), 256 thr, 2 float4 groups/thread (amortize reduction tail)
__global__ __launch_bounds__(256) void pass1(
    const float* __restrict__ pred, const int* __restrict__ masks,
    double* __restrict__ acc)
{
  const int b = blockIdx.y;
  const int tid = threadIdx.x;
  const float4* pb4 = (const float4*)(pred + (size_t)b * 12 * HW);
  const int4*   mk4 = (const int4*)(masks + (size_t)b * 8 * HW);

  float c[8] = {0}, cx[8] = {0}, cy[8] = {0}, sx[8] = {0}, sy[8] = {0},
        sxx[8] = {0}, syy[8] = {0};

#pragma unroll
  for (int k = 0; k < 2; k++) {
    const int g = blockIdx.x * 512 + k * 256 + tid;
    int idx = g << 2;
    int h = idx >> 10, w = idx & 1023;
    float4 p0 = pb4[g];
    float4 p1 = pb4[HW4 + g];
    float4 s0 = pb4[2 * HW4 + g];
    float4 s1 = pb4[3 * HW4 + g];
    int4 mv[8];
#pragma unroll
    for (int n = 0; n < 8; n++) mv[n] = mk4[n * HW4 + g];

    float p0v[4] = {p0.x, p0.y, p0.z, p0.w}, p1v[4] = {p1.x, p1.y, p1.z, p1.w};
    float s0v[4] = {s0.x, s0.y, s0.z, s0.w}, s1v[4] = {s1.x, s1.y, s1.z, s1.w};
    float exv[4], eyv[4];
#pragma unroll
    for (int j = 0; j < 4; j++) {
      exv[j] = ftanh(p0v[j]) + (float)((w + j) * (2.0 / 2047.0));
      eyv[j] = ftanh(p1v[j]) + (float)(h * (1.0 / 1023.0));
    }
#pragma unroll
    for (int n = 0; n < 8; n++) {
      int mvv[4] = {mv[n].x, mv[n].y, mv[n].z, mv[n].w};
#pragma unroll
      for (int j = 0; j < 4; j++) {
        float mf = (mvv[j] > 0) ? 1.f : 0.f;
        c[n] += mf; cx[n] += mf * exv[j]; cy[n] += mf * eyv[j];
        sx[n] += mf * s0v[j]; sy[n] += mf * s1v[j];
        sxx[n] += mf * s0v[j] * s0v[j]; syy[n] += mf * s1v[j] * s1v[j];
      }
    }
  }

  __shared__ float red[4][56];
  int lane = tid & 63, wid = tid >> 6;
#pragma unroll
  for (int n = 0; n < 8; n++) {
    float r0 = wred(c[n]),  r1 = wred(cx[n]), r2 = wred(cy[n]),
          r3 = wred(sx[n]), r4 = wred(sy[n]), r5 = wred(sxx[n]),
          r6 = wred(syy[n]);
    if (lane == 0) {
      red[wid][n * 7 + 0] = r0; red[wid][n * 7 + 1] = r1;
      red[wid][n * 7 + 2] = r2; red[wid][n * 7 + 3] = r3;
      red[wid][n * 7 + 4] = r4; red[wid][n * 7 + 5] = r5;
      red[wid][n * 7 + 6] = r6;
    }
  }
  __syncthreads();
  if (tid < 56) {
    float s = red[0][tid] + red[1][tid] + red[2][tid] + red[3][tid];
    int n = tid / 7, q = tid % 7;
    atomicAdd(&acc[((size_t)b * 8 + n) * 8 + q], (double)s);
  }
}

// ------- pass3 (merged): one block handles ALL 8 segs of batch b for its
// pixel chunk. ex/ey computed once per pixel; 8 packed histograms in LDS.
// grid (128, B), 1024 thr, 1 group/thread.
__global__ __launch_bounds__(1024) void pass3(
    const float* __restrict__ pred, const int* __restrict__ bbox,
    const int* __restrict__ masks, const int* __restrict__ cls_ids,
    double* __restrict__ acc, double* __restrict__ seedbg,
    unsigned long long* __restrict__ ghist)
{
  const int b = blockIdx.y;
  const int tid = threadIdx.x;
  __shared__ unsigned hist[8 * NBIN];        // packed: lo16=neg, hi16=pos (32 KB)
  __shared__ float cxs[8], cys[8], sxs[8], sys[8];
  __shared__ int clss[8];
  __shared__ float redf[16][9];
  for (int j = tid; j < 8 * NBIN; j += 1024) hist[j] = 0;
  if (tid < 8) {
    const double* a = acc + ((size_t)b * 8 + tid) * 8;
    double cs = a[0] < 1.0 ? 1.0 : a[0];
    cxs[tid] = (float)(a[1] / cs);
    cys[tid] = (float)(a[2] / cs);
    sxs[tid] = __expf((float)(a[3] / cs) * 10.f);
    sys[tid] = __expf((float)(a[4] / cs) * 10.f);
    clss[tid] = cls_ids[b * 8 + tid];
  }
  __syncthreads();

  const float4* pb4 = (const float4*)(pred + (size_t)b * 12 * HW);
  const int4*   mk4 = (const int4*)(masks + (size_t)b * 8 * HW);
  const int4*   bb4 = (const int4*)(bbox + (size_t)b * 9 * HW + HW); // ch 1..8
  const int g = blockIdx.x * 1024 + tid;
  int idx = g << 2;
  int h = idx >> 10, w = idx & 1023;

  float4 p0 = pb4[g];
  float4 p1 = pb4[HW4 + g];
  float p0v[4] = {p0.x, p0.y, p0.z, p0.w}, p1v[4] = {p1.x, p1.y, p1.z, p1.w};
  float ex[4], ey[4];
#pragma unroll
  for (int j = 0; j < 4; j++) {
    ex[j] = ftanh(p0v[j]) + (float)((w + j) * (2.0 / 2047.0));
    ey[j] = ftanh(p1v[j]) + (float)(h * (1.0 / 1023.0));
  }

  // seed_bg: stream channels, no storage
  float sbg = 0.f;
#pragma unroll
  for (int cc = 0; cc < 8; cc++) {
    float4 sv = pb4[(4 + cc) * HW4 + g];
    int4 bv = bb4[cc * HW4 + g];
    float svv[4] = {sv.x, sv.y, sv.z, sv.w};
    int bvv[4] = {bv.x, bv.y, bv.z, bv.w};
#pragma unroll
    for (int j = 0; j < 4; j++) {
      float s = fsig(svv[j]);
      sbg += (bvv[j] == 0) ? s * s : 0.f;
    }
  }

  // per-seg: dist, histogram, seed_fg (cls channel reloaded -> cache hit)
  float sf[8];
#pragma unroll
  for (int n = 0; n < 8; n++) sf[n] = 0.f;
#pragma unroll
  for (int n = 0; n < 8; n++) {
    int4 mv = mk4[n * HW4 + g];
    float4 sv = pb4[(4 + clss[n]) * HW4 + g];
    float cxn = cxs[n], cyn = cys[n], sxn = sxs[n], syn = sys[n];
    int mvv[4] = {mv.x, mv.y, mv.z, mv.w};
    float svv[4] = {sv.x, sv.y, sv.z, sv.w};
#pragma unroll
    for (int j = 0; j < 4; j++) {
      int m = (mvv[j] > 0) ? 1 : 0;
      float dx = ex[j] - cxn, dy = ey[j] - cyn;
      float d = __expf(-(dx * dx * sxn + dy * dy * syn));
      float df = fsig(svv[j]) - d;
      sf[n] += m ? df * df : 0.f;
      float e = m ? 2.f - 2.f * d : 2.f * d;
      int k = (int)(e * 512.f); k = k > (NBIN - 1) ? (NBIN - 1) : k;
      atomicAdd(&hist[n * NBIN + k], m ? 65536u : 1u);
    }
  }
  __syncthreads();

  // merge to global (one u64 atomic per nonzero bin)
  unsigned long long* gh = ghist + (size_t)b * 8 * NBIN;
  for (int j = tid; j < 8 * NBIN; j += 1024) {
    unsigned v = hist[j];
    if (v)
      atomicAdd(&gh[j], (unsigned long long)(v & 0xffffu) |
                        ((unsigned long long)(v >> 16) << 32));
  }

  // reductions: 8 seed_fg + 1 seed_bg
  int lane = tid & 63, wid = tid >> 6;
#pragma unroll
  for (int n = 0; n < 8; n++) {
    float r = wred(sf[n]);
    if (lane == 0) redf[wid][n] = r;
  }
  { float r = wred(sbg); if (lane == 0) redf[wid][8] = r; }
  __syncthreads();
  if (tid < 9) {
    float t = 0.f;
    for (int w2 = 0; w2 < 16; w2++) t += redf[w2][tid];
    if (tid < 8) atomicAdd(&acc[((size_t)b * 8 + tid) * 8 + 7], (double)t);
    else atomicAdd(&seedbg[b], (double)t);
  }
}

// ------- pass4: parallel closed-form Lovász + last-block final combine -------
// 16 blocks x 256 thr, 4 bins/thread. positive run at (p,C): grad = 1/(G+p-C);
// negative run n0: sum = (G-C)*(1/a - 1/(a+n0)), a = G+p-C.
__global__ __launch_bounds__(256) void pass4(
    const unsigned long long* __restrict__ ghist, const double* __restrict__ acc,
    const double* __restrict__ seedbg, const int* __restrict__ cls_ids,
    float* __restrict__ lov, unsigned* __restrict__ ctr,
    float* __restrict__ out)
{
  const int seg = blockIdx.x;
  const int tid = threadIdx.x;
  const int lane = tid & 63, wid = tid >> 6;
  __shared__ __align__(16) unsigned lh[NBIN * 2];   // [2k]=neg, [2k+1]=pos (8 KB)
  __shared__ unsigned wc[4], wp[4];
  __shared__ double sred[4];

  const uint4* gh4 = (const uint4*)(ghist + (size_t)seg * NBIN);
#pragma unroll
  for (int i = 0; i < 2; i++)
    ((uint4*)lh)[i * 256 + tid] = gh4[i * 256 + tid];
  __syncthreads();

  double G = acc[seg * 8 + 0];

  unsigned cntT = 0, posT = 0;
#pragma unroll
  for (int i = 0; i < 4; i++) {
    int kk = (NBIN - 1) - tid * 4 - i;
    unsigned h0 = lh[2 * kk], h1 = lh[2 * kk + 1];
    cntT += h0 + h1; posT += h1;
  }
  unsigned ic = cntT, ip = posT;
  for (int o = 1; o < 64; o <<= 1) {
    unsigned yc = __shfl_up(ic, o, 64), yp = __shfl_up(ip, o, 64);
    if (lane >= o) { ic += yc; ip += yp; }
  }
  if (lane == 63) { wc[wid] = ic; wp[wid] = ip; }
  __syncthreads();
  unsigned oc = 0, op = 0;
  for (int w2 = 0; w2 < wid; w2++) { oc += wc[w2]; op += wp[w2]; }
  unsigned p = oc + ic - cntT, C = op + ip - posT;   // exclusive prefix

  double S = 0.0;
#pragma unroll
  for (int i = 0; i < 4; i++) {
    int kk = (NBIN - 1) - tid * 4 - i;
    unsigned n1 = lh[2 * kk + 1], n0 = lh[2 * kk];
    double ec = (kk + 0.5) * (1.0 / 512.0);   // bin-center error value
    if (n1) {
      S += (double)n1 * ec / (G + (double)(p - C));
      p += n1; C += n1;
    }
    if (n0) {
      double rem = G - (double)C;
      if (rem > 0.0) {
        double aa = G + (double)(p - C);
        S += ec * rem * (1.0 / aa - 1.0 / (aa + (double)n0));
      }
      p += n0;
    }
  }
#pragma unroll
  for (int o = 32; o > 0; o >>= 1) S += __shfl_xor(S, o, 64);
  if (lane == 0) sred[wid] = S;
  __syncthreads();

  if (tid == 0) {
    double St = sred[0] + sred[1] + sred[2] + sred[3];
    atomicExch(&lov[seg], (float)St);
    __threadfence();
    unsigned old = atomicAdd(ctr, 1u);
    if (old == 15u) {                 // last block: final combine
      __threadfence();
      const float FG[8] = {10.f, 10.f, 10.f, 40.f, 80.f, 100.f, 60.f, 20.f};
      double total = 0.0;
      for (int b = 0; b < 2; b++) {
        double obj = 0, inst = 0, varl = 0, sfg = 0;
        for (int n = 0; n < 8; n++) {
          int s = b * 8 + n;
          const double* a = acc + s * 8;
          double cnt = a[0];
          double cs = cnt < 1.0 ? 1.0 : cnt;
          double smx = a[3] / cs, smy = a[4] / cs;
          double var = ((a[5] - cnt * smx * smx) + (a[6] - cnt * smy * smy)) /
                       (2.0 * cs);
          double v = (cnt >= 128.0) ? 1.0 : 0.0;
          double lv = (double)atomicAdd(&lov[s], 0.0f);   // coherent read
          obj += v;
          inst += lv * v;
          varl += var * v;
          sfg += (double)FG[cls_ids[s]] * a[7] * v;
        }
        double objs = obj < 1.0 ? 1.0 : obj;
        double seedl = (seedbg[b] + sfg) / (double)HW;
        total += inst / objs + 10.0 * (varl / objs) + seedl;
      }
      out[0] = (float)(0.5 * total);
    }
  }
}

extern "C" void kernel_launch(void* const* d_in, const int* in_sizes, int n_in,
                              void* d_out, int out_size, void* d_ws, size_t ws_size,
                              hipStream_t stream)
{
  (void)in_sizes; (void)n_in; (void)out_size; (void)ws_size;
  const float* pred  = (const float*)d_in[0];
  const int*   bbox  = (const int*)d_in[1];
  const int*   masks = (const int*)d_in[2];
  const int*   cls   = (const int*)d_in[3];

  char* ws = (char*)d_ws;
  double*             acc    = (double*)(ws + 0);       // 128 doubles
  double*             seedbg = (double*)(ws + 1024);    // 2 doubles
  float*              lov    = (float*)(ws + 1040);     // 16 floats
  unsigned*           ctr    = (unsigned*)(ws + 1104);  // 1 u32
  unsigned long long* ghist  = (unsigned long long*)(ws + 4096); // 16*NBIN u64

  hipMemsetAsync(d_ws, 0, 135168, stream);
  pass1<<<dim3(256, 2), 256, 0, stream>>>(pred, masks, acc);
  pass3<<<dim3(128, 2), 1024, 0, stream>>>(pred, bbox, masks, cls, acc, seedbg, ghist);
  pass4<<<16, 256, 0, stream>>>(ghist, acc, seedbg, cls, lov, ctr, (float*)d_out);
}

// Round 6
// 171.500 us; speedup vs baseline: 1.1236x; 1.1236x over previous
//
#include <hip/hip_runtime.h>
#include <cstdint>
#include <cstddef>

#define HW 524288      // H*W = 512*1024
#define HW4 131072     // float4/int4 groups per channel
#define NBIN 1024      // lovasz error histogram bins over [0,2]

// ws layout (bytes):
//   0    : double acc[16][8]  {cnt,cx,cy,sx,sy,sxx,syy,seedfg}     1024 B
//   1024 : double seedbg[2]                                          16 B
//   1040 : float  lov[16]                                            64 B
//   1104 : u32    ctr                                                 4 B
//   4096 : u64    ghist[16][NBIN]  (lo32=neg count, hi32=pos)    131072 B
// memset range: [0, 135168)

__device__ __forceinline__ float wred(float v) {
#pragma unroll
  for (int o = 32; o > 0; o >>= 1) v += __shfl_xor(v, o, 64);
  return v;
}

__device__ __forceinline__ float fsig(float x) {
  return __builtin_amdgcn_rcpf(1.f + __expf(-x));
}
__device__ __forceinline__ float ftanh(float x) {
  return 1.f - 2.f * __builtin_amdgcn_rcpf(__expf(2.f * x) + 1.f);
}

// ---------------- pass1: masked per-instance sums only ----------------
// grid (256, B), 256 thr, 2 float4 groups/thread (amortize reduction tail)
__global__ __launch_bounds__(256) void pass1(
    const float* __restrict__ pred, const int* __restrict__ masks,
    double* __restrict__ acc)
{
  const int b = blockIdx.y;
  const int tid = threadIdx.x;
  const float4* pb4 = (const float4*)(pred + (size_t)b * 12 * HW);
  const int4*   mk4 = (const int4*)(masks + (size_t)b * 8 * HW);

  float c[8] = {0}, cx[8] = {0}, cy[8] = {0}, sx[8] = {0}, sy[8] = {0},
        sxx[8] = {0}, syy[8] = {0};

#pragma unroll
  for (int k = 0; k < 2; k++) {
    const int g = blockIdx.x * 512 + k * 256 + tid;
    int idx = g << 2;
    int h = idx >> 10, w = idx & 1023;
    float4 p0 = pb4[g];
    float4 p1 = pb4[HW4 + g];
    float4 s0 = pb4[2 * HW4 + g];
    float4 s1 = pb4[3 * HW4 + g];
    int4 mv[8];
#pragma unroll
    for (int n = 0; n < 8; n++) mv[n] = mk4[n * HW4 + g];

    float p0v[4] = {p0.x, p0.y, p0.z, p0.w}, p1v[4] = {p1.x, p1.y, p1.z, p1.w};
    float s0v[4] = {s0.x, s0.y, s0.z, s0.w}, s1v[4] = {s1.x, s1.y, s1.z, s1.w};
    float exv[4], eyv[4];
#pragma unroll
    for (int j = 0; j < 4; j++) {
      exv[j] = ftanh(p0v[j]) + (float)((w + j) * (2.0 / 2047.0));
      eyv[j] = ftanh(p1v[j]) + (float)(h * (1.0 / 1023.0));
    }
#pragma unroll
    for (int n = 0; n < 8; n++) {
      int mvv[4] = {mv[n].x, mv[n].y, mv[n].z, mv[n].w};
#pragma unroll
      for (int j = 0; j < 4; j++) {
        float mf = (mvv[j] > 0) ? 1.f : 0.f;
        c[n] += mf; cx[n] += mf * exv[j]; cy[n] += mf * eyv[j];
        sx[n] += mf * s0v[j]; sy[n] += mf * s1v[j];
        sxx[n] += mf * s0v[j] * s0v[j]; syy[n] += mf * s1v[j] * s1v[j];
      }
    }
  }

  __shared__ float red[4][56];
  int lane = tid & 63, wid = tid >> 6;
#pragma unroll
  for (int n = 0; n < 8; n++) {
    float r0 = wred(c[n]),  r1 = wred(cx[n]), r2 = wred(cy[n]),
          r3 = wred(sx[n]), r4 = wred(sy[n]), r5 = wred(sxx[n]),
          r6 = wred(syy[n]);
    if (lane == 0) {
      red[wid][n * 7 + 0] = r0; red[wid][n * 7 + 1] = r1;
      red[wid][n * 7 + 2] = r2; red[wid][n * 7 + 3] = r3;
      red[wid][n * 7 + 4] = r4; red[wid][n * 7 + 5] = r5;
      red[wid][n * 7 + 6] = r6;
    }
  }
  __syncthreads();
  if (tid < 56) {
    float s = red[0][tid] + red[1][tid] + red[2][tid] + red[3][tid];
    int n = tid / 7, q = tid % 7;
    atomicAdd(&acc[((size_t)b * 8 + n) * 8 + q], (double)s);
  }
}

// ------- pass3: per-seg blocks (round-4 structure) + fast math + 4KB hist ----
// grid (32, 16 segs), 1024 thr (16 waves); block covers 16384 px = 4096 groups.
// seg-block n also handles bg-seed channel (4+n) and bbox channel (1+n).
// LDS hist packed: lo16 = neg count, hi16 = pos count (max 16384/block, fits).
__global__ __launch_bounds__(1024) void pass3(
    const float* __restrict__ pred, const int* __restrict__ bbox,
    const int* __restrict__ masks, const int* __restrict__ cls_ids,
    double* __restrict__ acc, double* __restrict__ seedbg,
    unsigned long long* __restrict__ ghist)
{
  const int seg = blockIdx.y;                 // 0..15 = b*8+n
  const int b = seg >> 3, n = seg & 7;
  const int tid = threadIdx.x;
  __shared__ unsigned hist[NBIN];             // 4 KB
  __shared__ float redf[16][2];
  for (int j = tid; j < NBIN; j += 1024) hist[j] = 0;

  const double* a = acc + seg * 8;
  double cntd = a[0];
  double cs = cntd < 1.0 ? 1.0 : cntd;
  float cxv = (float)(a[1] / cs), cyv = (float)(a[2] / cs);
  float sex = __expf((float)(a[3] / cs) * 10.f);
  float sey = __expf((float)(a[4] / cs) * 10.f);
  int cls = cls_ids[b * 8 + n];
  const float4* pb4 = (const float4*)(pred + (size_t)b * 12 * HW);
  const float4* sp4 = pb4 + (size_t)(4 + cls) * HW4;   // seed ch for cls
  const float4* sb4 = pb4 + (size_t)(4 + n) * HW4;     // bg-seed ch n
  const int4*   mp4 = (const int4*)(masks + (size_t)seg * HW);
  const int4*   bb4 = (const int4*)(bbox + (size_t)b * 9 * HW) + (1 + n) * HW4;
  __syncthreads();

  float sf = 0.f, sbg = 0.f;
  int gbase = blockIdx.x * 4096;
#pragma unroll
  for (int i = 0; i < 4; i++) {
    int g = gbase + i * 1024 + tid;
    int idx = g << 2;
    int h = idx >> 10, w = idx & 1023;
    float4 p0 = pb4[g];
    float4 p1 = pb4[HW4 + g];
    int4 mv = mp4[g];
    float4 sv = sp4[g];
    float4 sb = sb4[g];
    int4 bv = bb4[g];
    float p0v[4] = {p0.x, p0.y, p0.z, p0.w}, p1v[4] = {p1.x, p1.y, p1.z, p1.w};
    float svv[4] = {sv.x, sv.y, sv.z, sv.w}, sbv[4] = {sb.x, sb.y, sb.z, sb.w};
    int mvv[4] = {mv.x, mv.y, mv.z, mv.w}, bvv[4] = {bv.x, bv.y, bv.z, bv.w};
#pragma unroll
    for (int j = 0; j < 4; j++) {
      int m = (mvv[j] > 0) ? 1 : 0;
      float ex = ftanh(p0v[j]) + (float)((w + j) * (2.0 / 2047.0));
      float ey = ftanh(p1v[j]) + (float)(h * (1.0 / 1023.0));
      float dx = ex - cxv, dy = ey - cyv;
      float d = __expf(-(dx * dx * sex + dy * dy * sey));
      float df = fsig(svv[j]) - d;
      sf += m ? df * df : 0.f;
      float sgb = fsig(sbv[j]);
      sbg += (bvv[j] == 0) ? sgb * sgb : 0.f;
      float e = m ? 2.f - 2.f * d : 2.f * d;
      int k = (int)(e * 512.f); k = k > (NBIN - 1) ? (NBIN - 1) : k;
      atomicAdd(&hist[k], m ? 65536u : 1u);
    }
  }
  __syncthreads();

  // merge to global (one u64 atomic per nonzero bin)
  unsigned long long* gh = ghist + (size_t)seg * NBIN;
  for (int j = tid; j < NBIN; j += 1024) {
    unsigned v = hist[j];
    if (v)
      atomicAdd(&gh[j], (unsigned long long)(v & 0xffffu) |
                        ((unsigned long long)(v >> 16) << 32));
  }

  float r0 = wred(sf), r1 = wred(sbg);
  int lane = tid & 63, wid = tid >> 6;
  if (lane == 0) { redf[wid][0] = r0; redf[wid][1] = r1; }
  __syncthreads();
  if (tid == 0) {
    float t = 0.f;
    for (int w2 = 0; w2 < 16; w2++) t += redf[w2][0];
    atomicAdd(&acc[seg * 8 + 7], (double)t);
  } else if (tid == 64) {
    float t = 0.f;
    for (int w2 = 0; w2 < 16; w2++) t += redf[w2][1];
    atomicAdd(&seedbg[b], (double)t);
  }
}

// ------- pass4: parallel closed-form Lovász + last-block final combine -------
// 16 blocks x 256 thr, 4 bins/thread. positive run at (p,C): grad = 1/(G+p-C);
// negative run n0: sum = (G-C)*(1/a - 1/(a+n0)), a = G+p-C.
__global__ __launch_bounds__(256) void pass4(
    const unsigned long long* __restrict__ ghist, const double* __restrict__ acc,
    const double* __restrict__ seedbg, const int* __restrict__ cls_ids,
    float* __restrict__ lov, unsigned* __restrict__ ctr,
    float* __restrict__ out)
{
  const int seg = blockIdx.x;
  const int tid = threadIdx.x;
  const int lane = tid & 63, wid = tid >> 6;
  __shared__ __align__(16) unsigned lh[NBIN * 2];   // [2k]=neg, [2k+1]=pos (8 KB)
  __shared__ unsigned wc[4], wp[4];
  __shared__ double sred[4];

  const uint4* gh4 = (const uint4*)(ghist + (size_t)seg * NBIN);
#pragma unroll
  for (int i = 0; i < 2; i++)
    ((uint4*)lh)[i * 256 + tid] = gh4[i * 256 + tid];
  __syncthreads();

  double G = acc[seg * 8 + 0];

  unsigned cntT = 0, posT = 0;
#pragma unroll
  for (int i = 0; i < 4; i++) {
    int kk = (NBIN - 1) - tid * 4 - i;
    unsigned h0 = lh[2 * kk], h1 = lh[2 * kk + 1];
    cntT += h0 + h1; posT += h1;
  }
  unsigned ic = cntT, ip = posT;
  for (int o = 1; o < 64; o <<= 1) {
    unsigned yc = __shfl_up(ic, o, 64), yp = __shfl_up(ip, o, 64);
    if (lane >= o) { ic += yc; ip += yp; }
  }
  if (lane == 63) { wc[wid] = ic; wp[wid] = ip; }
  __syncthreads();
  unsigned oc = 0, op = 0;
  for (int w2 = 0; w2 < wid; w2++) { oc += wc[w2]; op += wp[w2]; }
  unsigned p = oc + ic - cntT, C = op + ip - posT;   // exclusive prefix

  double S = 0.0;
#pragma unroll
  for (int i = 0; i < 4; i++) {
    int kk = (NBIN - 1) - tid * 4 - i;
    unsigned n1 = lh[2 * kk + 1], n0 = lh[2 * kk];
    double ec = (kk + 0.5) * (1.0 / 512.0);   // bin-center error value
    if (n1) {
      S += (double)n1 * ec / (G + (double)(p - C));
      p += n1; C += n1;
    }
    if (n0) {
      double rem = G - (double)C;
      if (rem > 0.0) {
        double aa = G + (double)(p - C);
        S += ec * rem * (1.0 / aa - 1.0 / (aa + (double)n0));
      }
      p += n0;
    }
  }
#pragma unroll
  for (int o = 32; o > 0; o >>= 1) S += __shfl_xor(S, o, 64);
  if (lane == 0) sred[wid] = S;
  __syncthreads();

  if (tid == 0) {
    double St = sred[0] + sred[1] + sred[2] + sred[3];
    atomicExch(&lov[seg], (float)St);
    __threadfence();
    unsigned old = atomicAdd(ctr, 1u);
    if (old == 15u) {                 // last block: final combine
      __threadfence();
      const float FG[8] = {10.f, 10.f, 10.f, 40.f, 80.f, 100.f, 60.f, 20.f};
      double total = 0.0;
      for (int b = 0; b < 2; b++) {
        double obj = 0, inst = 0, varl = 0, sfg = 0;
        for (int n = 0; n < 8; n++) {
          int s = b * 8 + n;
          const double* a = acc + s * 8;
          double cnt = a[0];
          double cs = cnt < 1.0 ? 1.0 : cnt;
          double smx = a[3] / cs, smy = a[4] / cs;
          double var = ((a[5] - cnt * smx * smx) + (a[6] - cnt * smy * smy)) /
                       (2.0 * cs);
          double v = (cnt >= 128.0) ? 1.0 : 0.0;
          double lv = (double)atomicAdd(&lov[s], 0.0f);   // coherent read
          obj += v;
          inst += lv * v;
          varl += var * v;
          sfg += (double)FG[cls_ids[s]] * a[7] * v;
        }
        double objs = obj < 1.0 ? 1.0 : obj;
        double seedl = (seedbg[b] + sfg) / (double)HW;
        total += inst / objs + 10.0 * (varl / objs) + seedl;
      }
      out[0] = (float)(0.5 * total);
    }
  }
}

extern "C" void kernel_launch(void* const* d_in, const int* in_sizes, int n_in,
                              void* d_out, int out_size, void* d_ws, size_t ws_size,
                              hipStream_t stream)
{
  (void)in_sizes; (void)n_in; (void)out_size; (void)ws_size;
  const float* pred  = (const float*)d_in[0];
  const int*   bbox  = (const int*)d_in[1];
  const int*   masks = (const int*)d_in[2];
  const int*   cls   = (const int*)d_in[3];

  char* ws = (char*)d_ws;
  double*             acc    = (double*)(ws + 0);       // 128 doubles
  double*             seedbg = (double*)(ws + 1024);    // 2 doubles
  float*              lov    = (float*)(ws + 1040);     // 16 floats
  unsigned*           ctr    = (unsigned*)(ws + 1104);  // 1 u32
  unsigned long long* ghist  = (unsigned long long*)(ws + 4096); // 16*NBIN u64

  hipMemsetAsync(d_ws, 0, 135168, stream);
  pass1<<<dim3(256, 2), 256, 0, stream>>>(pred, masks, acc);
  pass3<<<dim3(32, 16), 1024, 0, stream>>>(pred, bbox, masks, cls, acc, seedbg, ghist);
  pass4<<<16, 256, 0, stream>>>(ghist, acc, seedbg, cls, lov, ctr, (float*)d_out);
}